// Round 18
// baseline (1407.204 us; speedup 1.0000x reference)
//
#include <hip/hip_runtime.h>

// Only the temporal (LSTM) branch of the reference reaches the output
// (h_gcn is dead). Per node:
//   xt_s = x[n, 52+s] * W_tp + b_tp          (rank-1, folded into A0/C0)
//   2-layer LSTM (H=32, T=12, torch gate order i,f,g,o)
//   out[n] = relu(h1 @ W_fc1 + b_fc1) @ W_fc2 + b_fc2
//
// v11 = v10 with LDS WEIGHT TRAFFIC HALVED: 2 nodes per lane.
//   Diagnosis (v8/v9/v10 all ~1250-1460 us): weights delivered from LDS =
//   48 KB/node/t = 57.6 GB total -> 835 us floor at 69 TB/s. The kernel
//   sits on this floor; scheduling can't beat it.
//   Fix: each lane processes nodes nA (slot) and nB (slot+64); every
//   weight window feeds two dot8's -> 28.8 GB -> ~418 us floor, 8 FMA
//   per ds_read_b128 instead of 4.
//   Register budget: h-state 32 + hn 16 + 8-load window 32 + partials 8
//   + temps ~15 = ~110 (c-state in per-thread LDS columns, 32 KB).
//   LDS 48+32 = 80 KB -> 2 blocks/CU x 4 waves = 8 waves/CU.
// Spill tell-tale: hbm_bytes >> 10 MB -> shrink windows to 4 loads.

#define TSTEPS 12
#define BS 256               // 4 waves per block
#define NPB 128              // nodes per block (2 per lane-quad slot)

__device__ __forceinline__ float fsig(float x) {
    float e = __expf(-x);                      // v_exp path; e in [0, inf)
    return __builtin_amdgcn_rcpf(1.0f + e);    // 1/(1+e), ~1 ulp
}

__device__ __forceinline__ float ftanh(float x) {
    float ax = fabsf(x);
    float e = __expf(-2.0f * ax);              // in (0,1], no overflow
    float r = (1.0f - e) * __builtin_amdgcn_rcpf(1.0f + e);
    return x < 0.0f ? -r : r;
}

// Repacked fold of layer-0 input matmul + biases, per OUTPUT j:
//   ws[j*8 + {0..3}] = A0 for gates i,f,g,o of j   (A0[r]=dot(Wih0[r,:],W_tp))
//   ws[j*8 + {4..7}] = C0 for gates i,f,g,o of j   (C0[r]=dot(Wih0[r,:],b_tp)+bih0[r]+bhh0[r])
//   ws[256 + j*4 + {0..3}] = C1 gates i,f,g,o      (bih1[r]+bhh1[r])
// where r = gate*32 + j.
__global__ void precomp_kernel(const float* __restrict__ Wih0,
                               const float* __restrict__ Wtp,
                               const float* __restrict__ btp,
                               const float* __restrict__ bih0,
                               const float* __restrict__ bhh0,
                               const float* __restrict__ bih1,
                               const float* __restrict__ bhh1,
                               float* __restrict__ ws) {
    int r = threadIdx.x;   // 0..127
    if (r < 128) {
        float a = 0.0f, c = 0.0f;
#pragma unroll
        for (int k = 0; k < 16; ++k) {
            float w = Wih0[r * 16 + k];
            a += w * Wtp[k];
            c += w * btp[k];
        }
        const int g4 = r >> 5;          // gate 0..3 (i,f,g,o)
        const int j  = r & 31;          // output index
        ws[j * 8 + g4]       = a;
        ws[j * 8 + 4 + g4]   = c + bih0[r] + bhh0[r];
        ws[256 + j * 4 + g4] = bih1[r] + bhh1[r];
    }
}

__device__ __forceinline__ float dot8(const float4 a0, const float4 a1,
                                      const float h[8]) {
    return a0.x*h[0] + a0.y*h[1] + a0.z*h[2] + a0.w*h[3]
         + a1.x*h[4] + a1.y*h[5] + a1.z*h[6] + a1.w*h[7];
}

// Reduce-scatter over a quad: inputs v0..v3 (per-g partials, all lanes),
// returns sum over the 4 lanes of v_s (s = lane&3). hi2=(s&2), hi1=(s&1).
__device__ __forceinline__ float rs4(float v0, float v1, float v2, float v3,
                                     bool hi2, bool hi1) {
    float sa = hi2 ? v0 : v2;     // give away first-of-other-pair
    float ka = hi2 ? v2 : v0;     // keep first-of-own-pair (g = s&2)
    float sb = hi2 ? v1 : v3;
    float kb = hi2 ? v3 : v1;     // g = (s&2)+1
    float u0 = ka + __shfl_xor(sa, 2);
    float u1 = kb + __shfl_xor(sb, 2);
    float sc = hi1 ? u0 : u1;
    float kc = hi1 ? u1 : u0;     // g = s
    return kc + __shfl_xor(sc, 1);
}

__global__ __launch_bounds__(BS) void lstm_kernel(
    const float* __restrict__ x,
    const float* __restrict__ Whh0,   // [128,32]
    const float* __restrict__ Wih1,   // [128,32]
    const float* __restrict__ Whh1,   // [128,32]
    const float* __restrict__ Wfc1,   // [32,16]
    const float* __restrict__ bfc1,   // [16]
    const float* __restrict__ Wfc2,   // [16]
    const float* __restrict__ bfc2,   // [1]
    const float* __restrict__ pre,    // [384] from precomp (repacked)
    float* __restrict__ out, int N)
{
    // 48 KB weights + 16 KB c0 + 16 KB c1 (2 nodes x 8 per thread) = 80 KB.
    __shared__ __align__(16) float sW[12288];
    __shared__ float sc0[16 * BS];    // [jj*BS+tid] node A, [2048+...] node B
    __shared__ float sc1[16 * BS];

    const int tid = threadIdx.x;
#pragma unroll
    for (int i = 0; i < 16; ++i) sW[i * BS + tid]        = Whh0[i * BS + tid];
#pragma unroll
    for (int i = 0; i < 16; ++i) sW[4096 + i * BS + tid] = Wih1[i * BS + tid];
#pragma unroll
    for (int i = 0; i < 16; ++i) sW[8192 + i * BS + tid] = Whh1[i * BS + tid];
#pragma unroll
    for (int jj = 0; jj < 8; ++jj) {   // own columns only, no extra sync
        sc0[jj * BS + tid] = 0.0f;  sc0[2048 + jj * BS + tid] = 0.0f;
        sc1[jj * BS + tid] = 0.0f;  sc1[2048 + jj * BS + tid] = 0.0f;
    }
    __syncthreads();                    // only barrier in the kernel

    const int s    = tid & 3;           // k-slice / j-group 0..3
    const int slot = tid >> 2;          // 0..63 within block
    const int so8  = s * 8;             // slice base (floats)
    const bool hi2 = (s & 2) != 0;
    const bool hi1 = (s & 1) != 0;
    const int nA = blockIdx.x * NPB + slot;         // node A
    const int nB = nA + 64;                         // node B
    const int nnA = (nA < N) ? nA : (N > 0 ? N - 1 : 0);
    const int nnB = (nB < N) ? nB : (N > 0 ? N - 1 : 0);
    const float* xrA = x + (size_t)nnA * 64 + 52;   // last 12 features
    const float* xrB = x + (size_t)nnB * 64 + 52;

    // Per-lane register state for TWO nodes. c lives in LDS.
    float h0A[8], h0B[8], h1A[8], h1B[8], hnA[8], hnB[8];
#pragma unroll
    for (int k = 0; k < 8; ++k) { h0A[k] = 0.0f; h0B[k] = 0.0f; h1A[k] = 0.0f; h1B[k] = 0.0f; }

#pragma unroll 1
    for (int t = 0; t < TSTEPS; ++t) {
        const float xvA = xrA[t];
        const float xvB = xrB[t];

        // ---------------- layer 0 ----------------
#pragma unroll
        for (int jj = 0; jj < 8; ++jj) {
            const int jown = so8 + jj;
            float SA[4], SB[4];
#pragma unroll
            for (int gate = 0; gate < 4; ++gate) {   // 8-load window
                float4 w0[4], w1[4];
#pragma unroll
                for (int g = 0; g < 4; ++g) {
                    const float* w = &sW[(gate * 32 + g * 8 + jj) * 32 + so8];
                    w0[g] = ((const float4*)w)[0];
                    w1[g] = ((const float4*)w)[1];
                }
                float pA[4], pB[4];
#pragma unroll
                for (int g = 0; g < 4; ++g) {        // each load feeds 2 dots
                    pA[g] = dot8(w0[g], w1[g], h0A);
                    pB[g] = dot8(w0[g], w1[g], h0B);
                }
                SA[gate] = rs4(pA[0], pA[1], pA[2], pA[3], hi2, hi1);
                SB[gate] = rs4(pB[0], pB[1], pB[2], pB[3], hi2, hi1);
                __builtin_amdgcn_sched_barrier(0);   // cap load window
            }
            const float4 pAq = ((const float4*)pre)[jown * 2];       // A0 quad
            const float4 pCq = ((const float4*)pre)[jown * 2 + 1];   // C0 quad
            {   // node A finish
                const float gi = SA[0] + pCq.x + xvA * pAq.x;
                const float gf = SA[1] + pCq.y + xvA * pAq.y;
                const float gG = SA[2] + pCq.z + xvA * pAq.z;
                const float go = SA[3] + pCq.w + xvA * pAq.w;
                const int ci = jj * BS + tid;
                const float cc = fsig(gf) * sc0[ci] + fsig(gi) * ftanh(gG);
                sc0[ci] = cc;
                hnA[jj] = fsig(go) * ftanh(cc);
            }
            {   // node B finish
                const float gi = SB[0] + pCq.x + xvB * pAq.x;
                const float gf = SB[1] + pCq.y + xvB * pAq.y;
                const float gG = SB[2] + pCq.z + xvB * pAq.z;
                const float go = SB[3] + pCq.w + xvB * pAq.w;
                const int ci = 2048 + jj * BS + tid;
                const float cc = fsig(gf) * sc0[ci] + fsig(gi) * ftanh(gG);
                sc0[ci] = cc;
                hnB[jj] = fsig(go) * ftanh(cc);
            }
        }
#pragma unroll
        for (int k = 0; k < 8; ++k) { h0A[k] = hnA[k]; h0B[k] = hnB[k]; }

        // ---------------- layer 1 ----------------
#pragma unroll
        for (int jj = 0; jj < 8; ++jj) {
            const int jown = so8 + jj;
            float SA[4], SB[4];
#pragma unroll
            for (int gate = 0; gate < 4; ++gate) {
                float pA[4], pB[4];
                {   // a-chunk: Wih1 . h0 (8 loads)
                    float4 w0[4], w1[4];
#pragma unroll
                    for (int g = 0; g < 4; ++g) {
                        const float* w = &sW[4096 + (gate * 32 + g * 8 + jj) * 32 + so8];
                        w0[g] = ((const float4*)w)[0];
                        w1[g] = ((const float4*)w)[1];
                    }
#pragma unroll
                    for (int g = 0; g < 4; ++g) {
                        pA[g] = dot8(w0[g], w1[g], h0A);
                        pB[g] = dot8(w0[g], w1[g], h0B);
                    }
                }
                __builtin_amdgcn_sched_barrier(0);
                {   // b-chunk: Whh1 . h1 (8 loads)
                    float4 w0[4], w1[4];
#pragma unroll
                    for (int g = 0; g < 4; ++g) {
                        const float* w = &sW[8192 + (gate * 32 + g * 8 + jj) * 32 + so8];
                        w0[g] = ((const float4*)w)[0];
                        w1[g] = ((const float4*)w)[1];
                    }
#pragma unroll
                    for (int g = 0; g < 4; ++g) {
                        pA[g] += dot8(w0[g], w1[g], h1A);
                        pB[g] += dot8(w0[g], w1[g], h1B);
                    }
                }
                SA[gate] = rs4(pA[0], pA[1], pA[2], pA[3], hi2, hi1);
                SB[gate] = rs4(pB[0], pB[1], pB[2], pB[3], hi2, hi1);
                __builtin_amdgcn_sched_barrier(0);
            }
            const float4 pD = ((const float4*)(pre + 256))[jown];   // C1 quad
            {   // node A finish
                const float gi = SA[0] + pD.x;
                const float gf = SA[1] + pD.y;
                const float gG = SA[2] + pD.z;
                const float go = SA[3] + pD.w;
                const int ci = jj * BS + tid;
                const float cc = fsig(gf) * sc1[ci] + fsig(gi) * ftanh(gG);
                sc1[ci] = cc;
                hnA[jj] = fsig(go) * ftanh(cc);
            }
            {   // node B finish
                const float gi = SB[0] + pD.x;
                const float gf = SB[1] + pD.y;
                const float gG = SB[2] + pD.z;
                const float go = SB[3] + pD.w;
                const int ci = 2048 + jj * BS + tid;
                const float cc = fsig(gf) * sc1[ci] + fsig(gi) * ftanh(gG);
                sc1[ci] = cc;
                hnB[jj] = fsig(go) * ftanh(cc);
            }
        }
#pragma unroll
        for (int k = 0; k < 8; ++k) { h1A[k] = hnA[k]; h1B[k] = hnB[k]; }
    }

    // epilogue: relu(h1 @ Wfc1 + bfc1) @ Wfc2 + bfc2, node A then node B
    {
        float am[16];
#pragma unroll
        for (int m = 0; m < 16; ++m) am[m] = 0.0f;
#pragma unroll 1
        for (int kk = 0; kk < 8; ++kk) {
            const float* row = Wfc1 + (size_t)(so8 + kk) * 16;
            const float4 r0 = ((const float4*)row)[0];
            const float4 r1 = ((const float4*)row)[1];
            const float4 r2 = ((const float4*)row)[2];
            const float4 r3 = ((const float4*)row)[3];
            const float hv = h1A[kk];
            am[ 0] += r0.x*hv; am[ 1] += r0.y*hv; am[ 2] += r0.z*hv; am[ 3] += r0.w*hv;
            am[ 4] += r1.x*hv; am[ 5] += r1.y*hv; am[ 6] += r1.z*hv; am[ 7] += r1.w*hv;
            am[ 8] += r2.x*hv; am[ 9] += r2.y*hv; am[10] += r2.z*hv; am[11] += r2.w*hv;
            am[12] += r3.x*hv; am[13] += r3.y*hv; am[14] += r3.z*hv; am[15] += r3.w*hv;
        }
        float acc = bfc2[0];
#pragma unroll
        for (int m = 0; m < 16; ++m) {
            float a = am[m];
            a += __shfl_xor(a, 1); a += __shfl_xor(a, 2);
            acc += fmaxf(a + bfc1[m], 0.0f) * Wfc2[m];
        }
        if (s == 0 && nA < N) out[nA] = acc;
    }
    {
        float am[16];
#pragma unroll
        for (int m = 0; m < 16; ++m) am[m] = 0.0f;
#pragma unroll 1
        for (int kk = 0; kk < 8; ++kk) {
            const float* row = Wfc1 + (size_t)(so8 + kk) * 16;
            const float4 r0 = ((const float4*)row)[0];
            const float4 r1 = ((const float4*)row)[1];
            const float4 r2 = ((const float4*)row)[2];
            const float4 r3 = ((const float4*)row)[3];
            const float hv = h1B[kk];
            am[ 0] += r0.x*hv; am[ 1] += r0.y*hv; am[ 2] += r0.z*hv; am[ 3] += r0.w*hv;
            am[ 4] += r1.x*hv; am[ 5] += r1.y*hv; am[ 6] += r1.z*hv; am[ 7] += r1.w*hv;
            am[ 8] += r2.x*hv; am[ 9] += r2.y*hv; am[10] += r2.z*hv; am[11] += r2.w*hv;
            am[12] += r3.x*hv; am[13] += r3.y*hv; am[14] += r3.z*hv; am[15] += r3.w*hv;
        }
        float acc = bfc2[0];
#pragma unroll
        for (int m = 0; m < 16; ++m) {
            float a = am[m];
            a += __shfl_xor(a, 1); a += __shfl_xor(a, 2);
            acc += fmaxf(a + bfc1[m], 0.0f) * Wfc2[m];
        }
        if (s == 0 && nB < N) out[nB] = acc;
    }
}

extern "C" void kernel_launch(void* const* d_in, const int* in_sizes, int n_in,
                              void* d_out, int out_size, void* d_ws, size_t ws_size,
                              hipStream_t stream) {
    (void)n_in; (void)out_size; (void)ws_size;
    // setup_inputs() order:
    // 0 x, 1 edge_index, 2 W_fp, 3 b_fp, 4 W_g1, 5 b_g1, 6 W_g2, 7 b_g2,
    // 8 W_g3, 9 b_g3, 10 W_tp, 11 b_tp, 12 Wih0, 13 Whh0, 14 bih0, 15 bhh0,
    // 16 Wih1, 17 Whh1, 18 bih1, 19 bhh1, 20 W_fc1, 21 b_fc1, 22 W_fc2, 23 b_fc2
    const float* x    = (const float*)d_in[0];
    const float* Wtp  = (const float*)d_in[10];
    const float* btp  = (const float*)d_in[11];
    const float* Wih0 = (const float*)d_in[12];
    const float* Whh0 = (const float*)d_in[13];
    const float* bih0 = (const float*)d_in[14];
    const float* bhh0 = (const float*)d_in[15];
    const float* Wih1 = (const float*)d_in[16];
    const float* Whh1 = (const float*)d_in[17];
    const float* bih1 = (const float*)d_in[18];
    const float* bhh1 = (const float*)d_in[19];
    const float* Wfc1 = (const float*)d_in[20];
    const float* bfc1 = (const float*)d_in[21];
    const float* Wfc2 = (const float*)d_in[22];
    const float* bfc2 = (const float*)d_in[23];

    float* out = (float*)d_out;
    float* pre = (float*)d_ws;   // 384 floats (repacked per-j layout)

    const int N = in_sizes[0] / 64;

    precomp_kernel<<<1, 128, 0, stream>>>(Wih0, Wtp, btp, bih0, bhh0, bih1, bhh1, pre);
    lstm_kernel<<<(N + NPB - 1) / NPB, BS, 0, stream>>>(
        x, Whh0, Wih1, Whh1, Wfc1, bfc1, Wfc2, bfc2, pre, out, N);
}